// Round 19
// baseline (22.001 us; speedup 1.0000x reference)
//
#include <hip/hip_runtime.h>
#include <hip/hip_bf16.h>
#include <math.h>

// Problem: B=8, M=N=4096, C=3, f32. Avg-Hausdorff (Chamfer), out (8,).
// d2(a,b) = sa + (sb - 2 a.b); paren term = rank-16 bf16 MFMA with fp32
// hi/lo splitting (absmax 0.0, R9-R17). Swapped operands (D = T x Q) keep
// the target-min lane-local (R12).
//
// R18: single compute dispatch. Cross-block min via DEVICE-SCOPE RELAXED
// atomicMin on monotone-transformed float bits (exact, order-independent
// -> deterministic). NO threadfences (R3's disaster was fence storms, not
// atomics). Election chain: last nseg-block per (g,qb) reduces 256 queries
// (sqrt+sum), atomicExch's a scalar; last elected block sums ssum[256] ->
// out[8]. Counters/keys re-init'd per call by one hipMemsetAsync(0xFF);
// election thresholds account for the 0xFF start (first old == 0xFFFFFFFF).
constexpr int NB   = 8;
constexpr int NPTS = 4096;
constexpr int NSEG = 4;            // n segments per (dir,batch)
constexpr int NN   = NPTS / NSEG;  // 1024 target points per block

typedef __attribute__((ext_vector_type(8)))  short  short8;
typedef __attribute__((ext_vector_type(16))) float  f32x16;

__device__ inline unsigned short f2bf(float v) {
    __hip_bfloat16 t = __float2bfloat16(v);
    return *reinterpret_cast<unsigned short*>(&t);
}
__device__ inline float bf2f(unsigned short u) {
    __hip_bfloat16 t = *reinterpret_cast<__hip_bfloat16*>(&u);
    return __bfloat162float(t);
}

// Monotone float->uint key (order-preserving for all finite floats).
__device__ inline unsigned fkey(float f) {
    unsigned b = __float_as_uint(f);
    return ((int)b < 0) ? ~b : (b | 0x80000000u);
}
__device__ inline float unfkey(unsigned k) {
    unsigned b = (k & 0x80000000u) ? (k & 0x7FFFFFFFu) : ~k;
    return __uint_as_float(b);
}

// grid = 16 g x 16 qblk x 4 nseg = 1024 blocks (4/CU, 4 waves/SIMD).
__global__ __launch_bounds__(256, 4) void hausdorff_kernel(
    const float* __restrict__ s1, const float* __restrict__ s2,
    unsigned* __restrict__ pmin, unsigned* __restrict__ ctr1,
    unsigned* __restrict__ ctr2, float* __restrict__ ssum,
    float* __restrict__ out)
{
    __shared__ short8 blds[2048];   // 32 KB, slot-ordered target fragments
    __shared__ float red[4];
    __shared__ float gsum[16];
    __shared__ unsigned flag;

    int bid  = blockIdx.x;
    int nseg = bid & 3;
    int qb   = (bid >> 2) & 15;
    int g    = bid >> 6;               // dir*8 + batch
    int b    = g & 7, dir = g >> 3;

    const float* Q    = dir ? s2 : s1;   // query set
    const float* Tset = dir ? s1 : s2;   // target set

    int tid = threadIdx.x;
    int wid = tid >> 6, l = tid & 63;
    int c = l & 31, h = l >> 5;

    // ---- Encode target segment into LDS (each thread: 4 points) ----
    const float* tsrc = Tset + ((size_t)b * NPTS + (size_t)nseg * NN) * 3;
    #pragma unroll
    for (int k = 0; k < 4; ++k) {
        int p = k * 256 + tid;           // 0..1023
        float x = tsrc[p*3+0], y = tsrc[p*3+1], z = tsrc[p*3+2];
        float sq = fmaf(z, z, fmaf(y, y, x * x));
        float tx = -2.0f*x, ty = -2.0f*y, tz = -2.0f*z;
        unsigned short thx = f2bf(tx), thy = f2bf(ty), thz = f2bf(tz);
        unsigned short tlx = f2bf(tx - bf2f(thx));
        unsigned short tly = f2bf(ty - bf2f(thy));
        unsigned short tlz = f2bf(tz - bf2f(thz));
        unsigned short sqh = f2bf(sq);
        unsigned short sql = f2bf(sq - bf2f(sqh));
        short8 tLo = {(short)thx,(short)thy,(short)thz,(short)thx,(short)thy,(short)thz,(short)sqh,(short)sql};
        short8 tHi = {(short)tlx,(short)tly,(short)tlz,0,0,0,0,0};
        int slot = (p >> 5) * 64 + (p & 31);
        blds[slot]      = tLo;
        blds[slot + 32] = tHi;
    }

    // ---- Encode this wave's 2 query fragments; keep coords for sa ----
    short8 qfr[2]; float qx[2], qy[2], qz[2];
    #pragma unroll
    for (int f = 0; f < 2; ++f) {
        int qidx = qb * 256 + wid * 64 + f * 32 + c;
        const float* qp = Q + ((size_t)b * NPTS + qidx) * 3;
        float x = qp[0], y = qp[1], z = qp[2];
        qx[f] = x; qy[f] = y; qz[f] = z;
        unsigned short ahx = f2bf(x), ahy = f2bf(y), ahz = f2bf(z);
        if (h == 0) {
            unsigned short alx = f2bf(x - bf2f(ahx));
            unsigned short aly = f2bf(y - bf2f(ahy));
            unsigned short alz = f2bf(z - bf2f(ahz));
            unsigned short one = 0x3F80;
            qfr[f] = short8{(short)ahx,(short)ahy,(short)ahz,
                            (short)alx,(short)aly,(short)alz,(short)one,(short)one};
        } else {
            qfr[f] = short8{(short)ahx,(short)ahy,(short)ahz,0,0,0,0,0};
        }
    }
    __syncthreads();

    f32x16 zero, acc0, acc1;
    #pragma unroll
    for (int r = 0; r < 16; ++r) { zero[r] = 0.0f; acc0[r] = 3.4e38f; acc1[r] = 3.4e38f; }

    for (int i = 0; i < 16; ++i) {            // 32 target tiles, in pairs
        short8 t0 = blds[(2*i  ) * 64 + l];    // lane-contiguous b128
        short8 t1 = blds[(2*i+1) * 64 + l];
        {
            f32x16 d0 = __builtin_amdgcn_mfma_f32_32x32x16_bf16(t0, qfr[0], zero, 0, 0, 0);
            f32x16 d1 = __builtin_amdgcn_mfma_f32_32x32x16_bf16(t1, qfr[0], zero, 0, 0, 0);
            #pragma unroll
            for (int r = 0; r < 16; ++r)
                acc0[r] = fminf(fminf(acc0[r], d0[r]), d1[r]);   // v_min3
        }
        {
            f32x16 d0 = __builtin_amdgcn_mfma_f32_32x32x16_bf16(t0, qfr[1], zero, 0, 0, 0);
            f32x16 d1 = __builtin_amdgcn_mfma_f32_32x32x16_bf16(t1, qfr[1], zero, 0, 0, 0);
            #pragma unroll
            for (int r = 0; r < 16; ++r)
                acc1[r] = fminf(fminf(acc1[r], d0[r]), d1[r]);
        }
    }

    // ---- Lane-local fold + 1 shfl; publish seg-min via exact atomicMin ----
    #pragma unroll
    for (int f = 0; f < 2; ++f) {
        f32x16& a = f ? acc1 : acc0;
        float v = a[0];
        #pragma unroll
        for (int r = 1; r < 16; ++r) v = fminf(v, a[r]);
        v = fminf(v, __shfl_xor(v, 32, 64));   // combine h halves
        if (h == 0) {
            float sa = fmaf(qz[f], qz[f], fmaf(qy[f], qy[f], qx[f] * qx[f]));
            int q = qb * 256 + wid * 64 + f * 32 + c;
            atomicMin(&pmin[(unsigned)g * NPTS + q], fkey(sa + v));
        }
    }

    // ---- Elect last nseg-block per (g,qb) (relaxed counter; vmcnt drained
    //      by the barrier, so all our atomicMins completed first) ----
    __syncthreads();
    if (tid == 0) {
        unsigned old = atomicAdd(&ctr1[g * 16 + qb], 1u);
        flag = (old == 2u) ? 1u : 0u;          // 0xFF-init: olds = FF,0,1,2
    }
    __syncthreads();
    if (!flag) return;

    // ---- Elected: finish 256 queries (read-min via atomic, sqrt, sum) ----
    {
        int q = qb * 256 + tid;
        unsigned key = atomicMin(&pmin[(unsigned)g * NPTS + q], 0xFFFFFFFFu); // pure read
        float d2 = unfkey(key);
        float s = sqrtf(fmaxf(d2, 0.0f));
        for (int off = 32; off > 0; off >>= 1)
            s += __shfl_down(s, off, 64);
        if (l == 0) red[wid] = s;
        __syncthreads();
        if (tid == 0) {
            float tot = red[0] + red[1] + red[2] + red[3];
            atomicExch(&ssum[g * 16 + qb], tot);
        }
        __syncthreads();                       // drain Exch before counting
        if (tid == 0) {
            unsigned old2 = atomicAdd(ctr2, 1u);
            flag = (old2 == 254u) ? 1u : 0u;   // 256 arrivals: FF,0,..,254
        }
        __syncthreads();
        if (!flag) return;
    }

    // ---- Final elected block: out[b] = (sum over qb & dirs) / M ----
    {
        unsigned kb = atomicOr(reinterpret_cast<unsigned*>(&ssum[tid]), 0u); // pure read
        float val = __uint_as_float(kb);
        val += __shfl_xor(val, 1, 64);
        val += __shfl_xor(val, 2, 64);
        val += __shfl_xor(val, 4, 64);
        val += __shfl_xor(val, 8, 64);         // 16-lane group sums (g = tid/16)
        if ((tid & 15) == 0) gsum[tid >> 4] = val;
        __syncthreads();
        if (tid < NB)
            out[tid] = (gsum[tid] + gsum[tid + 8]) * (1.0f / (float)NPTS);
    }
}

extern "C" void kernel_launch(void* const* d_in, const int* in_sizes, int n_in,
                              void* d_out, int out_size, void* d_ws, size_t ws_size,
                              hipStream_t stream) {
    const float* set1 = (const float*)d_in[0];
    const float* set2 = (const float*)d_in[1];
    float* out = (float*)d_out;

    unsigned char* ws = (unsigned char*)d_ws;
    unsigned* ctr1 = (unsigned*)ws;                 // 256 counters
    unsigned* ctr2 = (unsigned*)(ws + 1024);        // 1 counter
    float*    ssum = (float*)(ws + 1088);           // 256 floats
    unsigned* pmin = (unsigned*)(ws + 4096);        // 2*8*4096 keys = 256 KiB

    // One init covers counters (0xFF start, thresholds offset) + pmin keys
    // (0xFFFFFFFF = +inf key). ssum needs no init (atomicExch overwrites).
    hipMemsetAsync(ws, 0xFF, 4096 + (size_t)2 * NB * NPTS * 4, stream);

    hausdorff_kernel<<<16 * 16 * NSEG, 256, 0, stream>>>(
        set1, set2, pmin, ctr1, ctr2, ssum, out);
}

// Round 20
// 16.312 us; speedup vs baseline: 1.3488x; 1.3488x over previous
//
#include <hip/hip_runtime.h>
#include <hip/hip_bf16.h>
#include <math.h>

// Problem: B=8, M=N=4096, C=3, f32. Avg-Hausdorff (Chamfer), out (8,).
// d2(a,b) = sa + (sb - 2 a.b); paren term = rank-16 bf16 MFMA with fp32
// hi/lo splitting (absmax 0.0, R9-R18). Swapped operands (D = T x Q) keep
// the target-min lane-local (R12).
//
// R19: fewer, fatter blocks. R15/R18 decomposition showed single-shot k1
// carries ~10 us of launch ramp vs its 7.4 us marginal body, while k2+gap
// ~0.5 us. Theory: per-BLOCK dispatch rate. Grid 1024x256 -> 256x1024
// (same 4096 waves, same 4 waves/SIMD, 1 block/CU exactly). Each block
// covers 256 queries x ALL 4096 targets (4 q-groups x 4 segs = 16 waves;
// 128 KB LDS stage). Cross-seg min + sqrt + sum finish IN-BLOCK -> no pmin,
// no big k2; tiny final kernel combines partial[256] -> out[8].
constexpr int NB   = 8;
constexpr int NPTS = 4096;

typedef __attribute__((ext_vector_type(8)))  short  short8;
typedef __attribute__((ext_vector_type(16))) float  f32x16;

__device__ inline unsigned short f2bf(float v) {
    __hip_bfloat16 t = __float2bfloat16(v);
    return *reinterpret_cast<unsigned short*>(&t);
}
__device__ inline float bf2f(unsigned short u) {
    __hip_bfloat16 t = *reinterpret_cast<__hip_bfloat16*>(&u);
    return __bfloat162float(t);
}

// k1: grid = 16 g x 16 qb = 256 blocks x 1024 thr (16 waves, 4/SIMD).
// Wave wid: qg = wid&3 (64-query group), sg = wid>>2 (1024-target segment).
// Inner loop identical to R17's wave workload: 16 iters x {2 ds_read_b128 +
// 4 MFMA(T,Q) + 32 min3}.
__global__ __launch_bounds__(1024) void hausdorff_mfma_kernel(
    const float* __restrict__ s1, const float* __restrict__ s2,
    float* __restrict__ partial)
{
    __shared__ short8 blds[8192];        // 128 KB, slot-ordered target frags
    __shared__ float  qmin[4][256];      // 4 KB, per-seg query mins
    __shared__ float  red[4];

    int bid = blockIdx.x;
    int qb  = bid & 15;
    int g   = bid >> 4;                // dir*8 + batch
    int b   = g & 7, dir = g >> 3;

    const float* Q    = dir ? s2 : s1;   // query set
    const float* Tset = dir ? s1 : s2;   // target set

    int tid = threadIdx.x;
    int wid = tid >> 6, l = tid & 63;
    int c = l & 31, h = l >> 5;
    int qg = wid & 3, sg = wid >> 2;

    // ---- Encode ALL 4096 targets into LDS (each thread: 4 points) ----
    const float* tsrc = Tset + (size_t)b * NPTS * 3;
    #pragma unroll
    for (int k = 0; k < 4; ++k) {
        int p = k * 1024 + tid;          // 0..4095
        float x = tsrc[p*3+0], y = tsrc[p*3+1], z = tsrc[p*3+2];
        float sq = fmaf(z, z, fmaf(y, y, x * x));
        float tx = -2.0f*x, ty = -2.0f*y, tz = -2.0f*z;
        unsigned short thx = f2bf(tx), thy = f2bf(ty), thz = f2bf(tz);
        unsigned short tlx = f2bf(tx - bf2f(thx));
        unsigned short tly = f2bf(ty - bf2f(thy));
        unsigned short tlz = f2bf(tz - bf2f(thz));
        unsigned short sqh = f2bf(sq);
        unsigned short sql = f2bf(sq - bf2f(sqh));
        short8 tLo = {(short)thx,(short)thy,(short)thz,(short)thx,(short)thy,(short)thz,(short)sqh,(short)sql};
        short8 tHi = {(short)tlx,(short)tly,(short)tlz,0,0,0,0,0};
        int slot = (p >> 5) * 64 + (p & 31);
        blds[slot]      = tLo;
        blds[slot + 32] = tHi;
    }

    // ---- Encode this wave's 2 query fragments; keep coords for sa ----
    short8 qfr[2]; float qx[2], qy[2], qz[2];
    #pragma unroll
    for (int f = 0; f < 2; ++f) {
        int qidx = qb * 256 + qg * 64 + f * 32 + c;
        const float* qp = Q + ((size_t)b * NPTS + qidx) * 3;
        float x = qp[0], y = qp[1], z = qp[2];
        qx[f] = x; qy[f] = y; qz[f] = z;
        unsigned short ahx = f2bf(x), ahy = f2bf(y), ahz = f2bf(z);
        if (h == 0) {
            unsigned short alx = f2bf(x - bf2f(ahx));
            unsigned short aly = f2bf(y - bf2f(ahy));
            unsigned short alz = f2bf(z - bf2f(ahz));
            unsigned short one = 0x3F80;
            qfr[f] = short8{(short)ahx,(short)ahy,(short)ahz,
                            (short)alx,(short)aly,(short)alz,(short)one,(short)one};
        } else {
            qfr[f] = short8{(short)ahx,(short)ahy,(short)ahz,0,0,0,0,0};
        }
    }
    __syncthreads();

    f32x16 zero, acc0, acc1;
    #pragma unroll
    for (int r = 0; r < 16; ++r) { zero[r] = 0.0f; acc0[r] = 3.4e38f; acc1[r] = 3.4e38f; }

    const short8* bseg = blds + sg * 2048;    // this wave's 1024 targets
    for (int i = 0; i < 16; ++i) {            // 32 target tiles, in pairs
        short8 t0 = bseg[(2*i  ) * 64 + l];    // lane-contiguous b128
        short8 t1 = bseg[(2*i+1) * 64 + l];
        {
            f32x16 d0 = __builtin_amdgcn_mfma_f32_32x32x16_bf16(t0, qfr[0], zero, 0, 0, 0);
            f32x16 d1 = __builtin_amdgcn_mfma_f32_32x32x16_bf16(t1, qfr[0], zero, 0, 0, 0);
            #pragma unroll
            for (int r = 0; r < 16; ++r)
                acc0[r] = fminf(fminf(acc0[r], d0[r]), d1[r]);   // v_min3
        }
        {
            f32x16 d0 = __builtin_amdgcn_mfma_f32_32x32x16_bf16(t0, qfr[1], zero, 0, 0, 0);
            f32x16 d1 = __builtin_amdgcn_mfma_f32_32x32x16_bf16(t1, qfr[1], zero, 0, 0, 0);
            #pragma unroll
            for (int r = 0; r < 16; ++r)
                acc1[r] = fminf(fminf(acc1[r], d0[r]), d1[r]);
        }
    }

    // ---- Lane-local fold + 1 shfl; write sa + seg-min to qmin[sg][q] ----
    #pragma unroll
    for (int f = 0; f < 2; ++f) {
        f32x16& a = f ? acc1 : acc0;
        float v = a[0];
        #pragma unroll
        for (int r = 1; r < 16; ++r) v = fminf(v, a[r]);
        v = fminf(v, __shfl_xor(v, 32, 64));   // combine h halves
        if (h == 0) {
            float sa = fmaf(qz[f], qz[f], fmaf(qy[f], qy[f], qx[f] * qx[f]));
            qmin[sg][qg * 64 + f * 32 + c] = sa + v;
        }
    }
    __syncthreads();

    // ---- Finish in-block: min over 4 segs, clamp, sqrt, block-sum ----
    float s = 0.0f;
    if (tid < 256) {
        float m = fminf(fminf(qmin[0][tid], qmin[1][tid]),
                        fminf(qmin[2][tid], qmin[3][tid]));
        s = sqrtf(fmaxf(m, 0.0f));
    }
    for (int off = 32; off > 0; off >>= 1)
        s += __shfl_down(s, off, 64);
    if (wid < 4 && l == 0) red[wid] = s;
    __syncthreads();
    if (tid == 0)
        partial[bid] = red[0] + red[1] + red[2] + red[3];
}

// k2: 1 block, 64 threads: lane g<16 sums its 16 qb-partials; lanes b<8
// combine dir sums via shfl; out[b] = total / M.
__global__ __launch_bounds__(64) void final_kernel(
    const float* __restrict__ partial, float* __restrict__ out)
{
    int l = threadIdx.x;
    float s = 0.0f;
    if (l < 16) {
        #pragma unroll
        for (int j = 0; j < 16; ++j)
            s += partial[l * 16 + j];
    }
    float other = __shfl(s, l + 8, 64);    // lane b<8 gets g=8+b sum
    if (l < NB)
        out[l] = (s + other) * (1.0f / (float)NPTS);
}

extern "C" void kernel_launch(void* const* d_in, const int* in_sizes, int n_in,
                              void* d_out, int out_size, void* d_ws, size_t ws_size,
                              hipStream_t stream) {
    const float* set1 = (const float*)d_in[0];
    const float* set2 = (const float*)d_in[1];
    float* out     = (float*)d_out;
    float* partial = (float*)d_ws;   // 256 floats

    hausdorff_mfma_kernel<<<256, 1024, 0, stream>>>(set1, set2, partial);
    final_kernel<<<1, 64, 0, stream>>>(partial, out);
}